// Round 9
// baseline (194.569 us; speedup 1.0000x reference)
//
#include <hip/hip_runtime.h>
#include <cmath>

#define IH 128
#define IW 128
#define NB 8

typedef __attribute__((ext_vector_type(8))) short bf16x8;
typedef __attribute__((ext_vector_type(4))) float f32x4;
typedef __attribute__((ext_vector_type(2))) float f32x2;

union U4B8 { uint4 u; bf16x8 h; };

// ws layout (float slots):
//   offm  : [NB][27][IH][IW] f32      = 3538944
//   xT    : [NB][IH][IW][64] bf16     = 4194304 float slots (8388608 u16)
//   wt_dc : [9][64][64] bf16 (k,o,c)  = 18432 float slots
//   wt_om : [9][32][64] bf16 (k,o,c)  = 9216  float slots
#define OFFM_OFF 0
#define XT_OFF   3538944
#define WTDC_OFF (3538944 + 4194304)
#define WTOM_OFF (3538944 + 4194304 + 18432)

// fp32 -> bf16 bits, round-to-nearest-even
__device__ __forceinline__ unsigned short f32_to_bf16(float f) {
    unsigned int u = __float_as_uint(f);
    u += 0x7fffu + ((u >> 16) & 1u);
    return (unsigned short)(u >> 16);
}

// ---------------------------------------------------------------------------
// Kernel 0: weights -> bf16, layout [k][o][c]
// ---------------------------------------------------------------------------
__global__ void transpose_weights(const float* __restrict__ w_dc,
                                  const float* __restrict__ w_om,
                                  unsigned short* __restrict__ wt_dc16,
                                  unsigned short* __restrict__ wt_om16) {
    int idx = blockIdx.x * blockDim.x + threadIdx.x;
    if (idx < 9 * 64 * 64) {
        int k = idx >> 12;
        int o = (idx >> 6) & 63;
        int c = idx & 63;
        wt_dc16[idx] = f32_to_bf16(w_dc[(o * 64 + c) * 9 + k]);
    }
    if (idx < 9 * 32 * 64) {
        int k = idx >> 11;
        int o = (idx >> 6) & 31;
        int c = idx & 63;
        wt_om16[idx] = (o < 27) ? f32_to_bf16(w_om[(o * 64 + c) * 9 + k])
                                : (unsigned short)0;
    }
}

// ---------------------------------------------------------------------------
// Kernel 0b: x NCHW fp32 -> NHWC bf16 (xT[b][y][x][c]) — vectorized (R6).
// ---------------------------------------------------------------------------
__global__ __launch_bounds__(256) void transpose_x(
        const float* __restrict__ x, unsigned short* __restrict__ xT) {
    __shared__ __align__(16) float t[64][132];   // 132: 16B-aligned rows, +pad
    const int tid = threadIdx.x;
    const int b = blockIdx.x >> 7;
    const int h = blockIdx.x & 127;

#pragma unroll
    for (int j = 0; j < 8; ++j) {
        const int i = (j << 8) + tid;       // 0..2047
        const int c = i >> 5;               // 0..63
        const int w4 = i & 31;              // float4 index within row
        const float4 v = *(const float4*)&x[(((size_t)(b * 64 + c)) << 14) + (h << 7) + (w4 << 2)];
        *(float4*)&t[c][w4 << 2] = v;
    }
    __syncthreads();

#pragma unroll
    for (int j = 0; j < 4; ++j) {
        const int u = (j << 8) + tid;       // 0..1023
        const int px = u & 127;
        const int cg = u >> 7;              // channel-group of 8
        unsigned int pk[4];
#pragma unroll
        for (int e = 0; e < 4; ++e) {
            const float lo = t[(cg << 3) + 2 * e][px];
            const float hi = t[(cg << 3) + 2 * e + 1][px];
            asm("v_cvt_pk_bf16_f32 %0, %1, %2" : "=v"(pk[e]) : "v"(lo), "v"(hi));
        }
        *(uint4*)(xT + (((size_t)b << 20) + ((size_t)((h << 7) + px) << 6) + (cg << 3))) =
            make_uint4(pk[0], pk[1], pk[2], pk[3]);
    }
}

// ---------------------------------------------------------------------------
// Kernel 1: conv3x3 -> offset/mask (R3 version verbatim — proven).
// ---------------------------------------------------------------------------
__global__ __launch_bounds__(256) void conv_om_mfma(
        const unsigned short* __restrict__ xT,
        const float* __restrict__ b_om,
        const unsigned short* __restrict__ wt_om16,  // [9][32][64]
        float* __restrict__ offm) {
    __shared__ __align__(16) unsigned short win[198 * 72];   // [3*66][72]
    __shared__ __align__(16) unsigned short wks[2][32 * 72]; // [buf][o][72]

    const int tid = threadIdx.x;
    const int bid = blockIdx.x;
    const int swz = ((bid & 7) << 8) + (bid >> 3);   // XCD-contiguous
    const int b = swz >> 8;
    const int rem = swz & 255;
    const int h = rem >> 1;
    const int w0 = (rem & 1) << 6;
    const int wid = tid >> 6;
    const int lane = tid & 63;
    const int ln15 = lane & 15;
    const int quad = lane >> 4;

    for (int idx = tid; idx < 1584; idx += 256) {
        const int pos = idx >> 3;
        const int part = idx & 7;
        const int r = pos / 66;
        const int xx = pos - r * 66;
        const int y = h + r - 1;
        const int xg = w0 + xx - 1;
        uint4 v = make_uint4(0u, 0u, 0u, 0u);
        if (y >= 0 && y < IH && xg >= 0 && xg < IW)
            v = *(const uint4*)(xT + (((size_t)b << 20) + (((y << 7) + xg) << 6) + (part << 3)));
        *(uint4*)&win[pos * 72 + part * 8] = v;
    }
    {
        const int o = tid >> 3;
        const int part = tid & 7;
        *(uint4*)&wks[0][o * 72 + part * 8] =
            *(const uint4*)(wt_om16 + (o << 6) + (part << 3));
    }
    __syncthreads();

    f32x4 acc[2] = {{0.f, 0.f, 0.f, 0.f}, {0.f, 0.f, 0.f, 0.f}};

    for (int k = 0; k < 9; ++k) {
        const int buf = k & 1;
        if (k < 8) {
            const int o = tid >> 3;
            const int part = tid & 7;
            *(uint4*)&wks[buf ^ 1][o * 72 + part * 8] =
                *(const uint4*)(wt_om16 + ((k + 1) << 11) + (o << 6) + (part << 3));
        }
        const int kh = k / 3;
        const int kw = k - kh * 3;
        const int posb = kh * 66 + wid * 16 + ln15 + kw;
        const unsigned short* wb = wks[buf];
#pragma unroll
        for (int ch = 0; ch < 2; ++ch) {
            const int c = (ch << 5) + (quad << 3);
            U4B8 a, b0, b1;
            a.u  = *(const uint4*)&win[posb * 72 + c];
            b0.u = *(const uint4*)&wb[ln15 * 72 + c];
            b1.u = *(const uint4*)&wb[(16 + ln15) * 72 + c];
            acc[0] = __builtin_amdgcn_mfma_f32_16x16x32_bf16(a.h, b0.h, acc[0], 0, 0, 0);
            acc[1] = __builtin_amdgcn_mfma_f32_16x16x32_bf16(a.h, b1.h, acc[1], 0, 0, 0);
        }
        __syncthreads();
    }

    const int px0 = wid * 16 + quad * 4;
#pragma unroll
    for (int ot = 0; ot < 2; ++ot) {
        const int o = (ot << 4) + ln15;
        if (o >= 27) continue;
        const float bias = b_om[o];
        float4 r;
        r.x = acc[ot][0] + bias;
        r.y = acc[ot][1] + bias;
        r.z = acc[ot][2] + bias;
        r.w = acc[ot][3] + bias;
        if (o >= 18) {
            r.x = 2.0f / (1.0f + __expf(-r.x));
            r.y = 2.0f / (1.0f + __expf(-r.y));
            r.z = 2.0f / (1.0f + __expf(-r.z));
            r.w = 2.0f / (1.0f + __expf(-r.w));
        }
        *(float4*)&offm[(((size_t)(b * 27 + o)) << 14) + (h << 7) + w0 + px0] = r;
    }
}

// ---------------------------------------------------------------------------
// gather issue phase: compute corner weights (msk premultiplied) and ISSUE
// the 8 corner loads into registers. Consumed one tap later.
// offs is LDS, stride 64 floats per channel (64-px blocks).
// ---------------------------------------------------------------------------
__device__ __forceinline__ void issue_gather(
        const unsigned short* __restrict__ xb, const float* offs,
        int k, int lpx, int h, int w0, int quad, uint4* g, float* cw) {
    const float offy = offs[(k << 1) * 64 + lpx];
    const float offx = offs[((k << 1) + 1) * 64 + lpx];
    const float msk  = offs[(18 + k) * 64 + lpx];
    const int kh = k / 3;
    const int kw = k - kh * 3;
    const float py  = (float)(h + kh - 1) + offy;
    const float pxf = (float)(w0 + lpx + kw - 1) + offx;
    const float y0f = floorf(py);
    const float x0f = floorf(pxf);
    const float fy = py - y0f;
    const float fx = pxf - x0f;
    const float wy0 = 1.0f - fy, wx0 = 1.0f - fx;
    const float vy0 = (y0f >= 0.0f && y0f <= 127.0f) ? 1.0f : 0.0f;
    const float vy1 = (y0f >= -1.0f && y0f <= 126.0f) ? 1.0f : 0.0f;
    const float vx0 = (x0f >= 0.0f && x0f <= 127.0f) ? 1.0f : 0.0f;
    const float vx1 = (x0f >= -1.0f && x0f <= 126.0f) ? 1.0f : 0.0f;
    cw[0] = wy0 * wx0 * vy0 * vx0 * msk;
    cw[1] = wy0 * fx  * vy0 * vx1 * msk;
    cw[2] = fy  * wx0 * vy1 * vx0 * msk;
    cw[3] = fy  * fx  * vy1 * vx1 * msk;
    const int y0i = min(max((int)y0f, 0), 127);
    const int y1i = min(max((int)y0f + 1, 0), 127);
    const int x0i = min(max((int)x0f, 0), 127);
    const int x1i = min(max((int)x0f + 1, 0), 127);
    const int cofs = quad << 3;
    const unsigned short* p00 = xb + ((((size_t)((y0i << 7) + x0i)) << 6) + cofs);
    const unsigned short* p01 = xb + ((((size_t)((y0i << 7) + x1i)) << 6) + cofs);
    const unsigned short* p10 = xb + ((((size_t)((y1i << 7) + x0i)) << 6) + cofs);
    const unsigned short* p11 = xb + ((((size_t)((y1i << 7) + x1i)) << 6) + cofs);
    g[0] = *(const uint4*)p00;  g[1] = *(const uint4*)(p00 + 32);
    g[2] = *(const uint4*)p01;  g[3] = *(const uint4*)(p01 + 32);
    g[4] = *(const uint4*)p10;  g[5] = *(const uint4*)(p10 + 32);
    g[6] = *(const uint4*)p11;  g[7] = *(const uint4*)(p11 + 32);
}

// ---------------------------------------------------------------------------
// consume phase: combine 8 corner vectors with 4 (msk-premul) weights via
// packed-f32 FMA, pack to bf16 A-fragments via hw cvt_pk.
// ---------------------------------------------------------------------------
__device__ __forceinline__ void pack_frags(const uint4* g, const float* cw,
                                           U4B8& a0, U4B8& a1) {
    f32x2 v2[8];
#pragma unroll
    for (int i = 0; i < 8; ++i) v2[i] = (f32x2){0.f, 0.f};
#pragma unroll
    for (int c = 0; c < 4; ++c) {
        f32x2 w2;
        w2.x = cw[c];
        w2.y = cw[c];
        const uint4 ga = g[2 * c];
        const uint4 gb = g[2 * c + 1];
        const unsigned int u[8] = {ga.x, ga.y, ga.z, ga.w, gb.x, gb.y, gb.z, gb.w};
#pragma unroll
        for (int i = 0; i < 8; ++i) {
            f32x2 x2;
            x2.x = __uint_as_float(u[i] << 16);
            x2.y = __uint_as_float(u[i] & 0xffff0000u);
            asm("v_pk_fma_f32 %0, %1, %2, %0" : "+v"(v2[i]) : "v"(x2), "v"(w2));
        }
    }
    unsigned int pk[8];
#pragma unroll
    for (int i = 0; i < 8; ++i)
        asm("v_cvt_pk_bf16_f32 %0, %1, %2"
            : "=v"(pk[i]) : "v"(v2[i].x), "v"(v2[i].y));
    a0.u = make_uint4(pk[0], pk[1], pk[2], pk[3]);
    a1.u = make_uint4(pk[4], pk[5], pk[6], pk[7]);
}

// ---------------------------------------------------------------------------
// Kernel 2: deformable conv. Block = 64px x 64o, 4 waves (16px x 64o each).
// ALL 9 weight slices staged into LDS once (72 KB, XOR-swizzled
// byte ^= (row&7)<<4 to break the stride-128B bank conflict) -> the k-loop
// has NO weight loads, NO ds_writes, NO barriers. Only VMEM in the loop is
// the 8 gather loads, register-pipelined one tap ahead.
// __launch_bounds__(256,2): VGPR cap 256 so regalloc can keep g[2][8] live
// (R7's VGPR=64 proved the compiler squashed the pipeline to hit the 64-reg
// occupancy step, re-serializing every gather).
// LDS 79 KB -> 2 blocks/CU. XCD swizzle: each XCD owns one image.
// ---------------------------------------------------------------------------
__global__ __launch_bounds__(256, 2) void deform_mfma(
        const unsigned short* __restrict__ xT,
        const float* __restrict__ b_dc,
        const float* __restrict__ offm,              // [B][27][H][W]
        const unsigned short* __restrict__ wt_dc16,  // [9][64][64] (k,o,c)
        float* __restrict__ out) {
    __shared__ float offs[27 * 64];                            // [ch][px]
    __shared__ __align__(16) unsigned short wksAll[9 * 64 * 64]; // swizzled

    const int tid = threadIdx.x;
    const int bid = blockIdx.x;
    const int swz = ((bid & 7) << 8) + (bid >> 3);   // XCD-contiguous
    const int b = swz >> 8;
    const int rem = swz & 255;
    const int h = rem >> 1;
    const int w0 = (rem & 1) << 6;
    const int wid = tid >> 6;
    const int lane = tid & 63;
    const int ln15 = lane & 15;
    const int quad = lane >> 4;
    const int lpx = (wid << 4) + ln15;   // local pixel this lane gathers/owns

    // stage offsets/masks for the block's 64 pixels
    for (int i = tid; i < 1728; i += 256) {
        offs[i] = offm[(((size_t)(b * 27 + (i >> 6))) << 14) + (h << 7) + w0 + (i & 63)];
    }
    // stage ALL 9 weight slices, XOR-swizzled: byte col ^= (row&7)<<4
    for (int s = tid; s < 9 * 512; s += 256) {
        const int slice = s >> 9;
        const int idx = s & 511;
        const int o = idx >> 3;          // row 0..63
        const int sp = idx & 7;          // 16B part
        const int col = (sp << 4) ^ ((o & 7) << 4);   // swizzled byte col
        *(uint4*)&wksAll[(slice << 12) + (o << 6) + (col >> 1)] =
            *(const uint4*)(wt_dc16 + (slice << 12) + (o << 6) + (sp << 3));
    }
    __syncthreads();

    const unsigned short* xb = xT + ((size_t)b << 20);

    f32x4 acc[4];
#pragma unroll
    for (int i = 0; i < 4; ++i) acc[i] = (f32x4){0.f, 0.f, 0.f, 0.f};

    uint4 g[2][8];
    float cw[2][4];
    issue_gather(xb, offs, 0, lpx, h, w0, quad, g[0], cw[0]);

#pragma unroll
    for (int k = 0; k < 9; ++k) {
        const int cur = k & 1;
        const int nxt = cur ^ 1;
        if (k < 8) {
            // issue next-tap gather loads (only VMEM in the loop; one full
            // tap of latency hiding; no barrier ever drains them)
            issue_gather(xb, offs, k + 1, lpx, h, w0, quad, g[nxt], cw[nxt]);
        }
        // pack tap k from last iteration's registers
        U4B8 a0, a1;
        pack_frags(g[cur], cw[cur], a0, a1);
        // MFMA from pre-staged swizzled LDS weights
        const unsigned short* wb = &wksAll[k << 12];
#pragma unroll
        for (int ot = 0; ot < 4; ++ot) {
            const int row = (ot << 4) + ln15;
            const int xr = (row & 7) << 4;
            const int c0 = ((quad << 4) ^ xr) >> 1;          // b0 swizzled col
            const int c1 = ((64 + (quad << 4)) ^ xr) >> 1;   // b1 swizzled col
            U4B8 b0, b1;
            b0.u = *(const uint4*)&wb[(row << 6) + c0];
            b1.u = *(const uint4*)&wb[(row << 6) + c1];
            acc[ot] = __builtin_amdgcn_mfma_f32_16x16x32_bf16(a0.h, b0.h, acc[ot], 0, 0, 0);
            acc[ot] = __builtin_amdgcn_mfma_f32_16x16x32_bf16(a1.h, b1.h, acc[ot], 0, 0, 0);
        }
    }

    // epilogue: col(o)=lane&15, row(px)=quad*4+reg
#pragma unroll
    for (int ot = 0; ot < 4; ++ot) {
        const int o = (ot << 4) + ln15;
        const float bias = b_dc[o];
        float4 r;
        r.x = acc[ot][0] + bias;
        r.y = acc[ot][1] + bias;
        r.z = acc[ot][2] + bias;
        r.w = acc[ot][3] + bias;
        *(float4*)&out[(((size_t)(b * 64 + o)) << 14) + (h << 7) + w0 + (wid << 4) + (quad << 2)] = r;
    }
}

extern "C" void kernel_launch(void* const* d_in, const int* in_sizes, int n_in,
                              void* d_out, int out_size, void* d_ws, size_t ws_size,
                              hipStream_t stream) {
    const float* x    = (const float*)d_in[0];
    const float* w_om = (const float*)d_in[1];
    const float* b_om = (const float*)d_in[2];
    const float* w_dc = (const float*)d_in[3];
    const float* b_dc = (const float*)d_in[4];
    float* out = (float*)d_out;
    float* ws  = (float*)d_ws;

    float* offm = ws + OFFM_OFF;
    unsigned short* xT      = (unsigned short*)(ws + XT_OFF);
    unsigned short* wt_dc16 = (unsigned short*)(ws + WTDC_OFF);
    unsigned short* wt_om16 = (unsigned short*)(ws + WTOM_OFF);

    transpose_weights<<<144, 256, 0, stream>>>(w_dc, w_om, wt_dc16, wt_om16);
    transpose_x<<<NB * IH, 256, 0, stream>>>(x, xT);
    conv_om_mfma<<<NB * IH * 2, 256, 0, stream>>>(xT, b_om, wt_om16, offm);
    deform_mfma<<<NB * IH * 2, 256, 0, stream>>>(xT, b_dc, offm, wt_dc16, out);
}

// Round 10
// 184.967 us; speedup vs baseline: 1.0519x; 1.0519x over previous
//
#include <hip/hip_runtime.h>
#include <cmath>

#define IH 128
#define IW 128
#define NB 8
#define OFFS_STRIDE 129

typedef __attribute__((ext_vector_type(8))) short bf16x8;
typedef __attribute__((ext_vector_type(4))) float f32x4;
typedef __attribute__((ext_vector_type(2))) float f32x2;

union U4B8 { uint4 u; bf16x8 h; };

// ws layout (float slots):
//   offm  : [NB][27][IH][IW] f32      = 3538944
//   xT    : [NB][IH][IW][64] bf16     = 4194304 float slots (8388608 u16)
//   wt_dc : [9][64][64] bf16 (k,o,c)  = 18432 float slots
//   wt_om : [9][32][64] bf16 (k,o,c)  = 9216  float slots
#define OFFM_OFF 0
#define XT_OFF   3538944
#define WTDC_OFF (3538944 + 4194304)
#define WTOM_OFF (3538944 + 4194304 + 18432)

// fp32 -> bf16 bits, round-to-nearest-even
__device__ __forceinline__ unsigned short f32_to_bf16(float f) {
    unsigned int u = __float_as_uint(f);
    u += 0x7fffu + ((u >> 16) & 1u);
    return (unsigned short)(u >> 16);
}

// ---------------------------------------------------------------------------
// Kernel 0: x NCHW fp32 -> NHWC bf16 (blocks 0..1023, vectorized R6 path)
//           + weights -> bf16 [k][o][c] (blocks 1024..1167) — merged to save
//           one launch (~63 µs fixed overhead identified across R5/R6/R7;
//           every launch removed chips at it).
// ---------------------------------------------------------------------------
__global__ __launch_bounds__(256) void transpose_x_w(
        const float* __restrict__ x, unsigned short* __restrict__ xT,
        const float* __restrict__ w_dc, const float* __restrict__ w_om,
        unsigned short* __restrict__ wt_dc16,
        unsigned short* __restrict__ wt_om16) {
    __shared__ __align__(16) float t[64][132];   // 132: 16B-aligned rows, +pad
    const int tid = threadIdx.x;
    const int blk = blockIdx.x;

    if (blk >= NB * IH) {            // weight-transpose tail blocks
        const int idx = (blk - NB * IH) * 256 + tid;
        if (idx < 9 * 64 * 64) {
            const int k = idx >> 12;
            const int o = (idx >> 6) & 63;
            const int c = idx & 63;
            wt_dc16[idx] = f32_to_bf16(w_dc[(o * 64 + c) * 9 + k]);
        }
        if (idx < 9 * 32 * 64) {
            const int k = idx >> 11;
            const int o = (idx >> 6) & 31;
            const int c = idx & 63;
            wt_om16[idx] = (o < 27) ? f32_to_bf16(w_om[(o * 64 + c) * 9 + k])
                                    : (unsigned short)0;
        }
        return;
    }

    const int b = blk >> 7;
    const int h = blk & 127;

#pragma unroll
    for (int j = 0; j < 8; ++j) {
        const int i = (j << 8) + tid;       // 0..2047
        const int c = i >> 5;               // 0..63
        const int w4 = i & 31;              // float4 index within row
        const float4 v = *(const float4*)&x[(((size_t)(b * 64 + c)) << 14) + (h << 7) + (w4 << 2)];
        *(float4*)&t[c][w4 << 2] = v;
    }
    __syncthreads();

#pragma unroll
    for (int j = 0; j < 4; ++j) {
        const int u = (j << 8) + tid;       // 0..1023
        const int px = u & 127;
        const int cg = u >> 7;              // channel-group of 8
        unsigned int pk[4];
#pragma unroll
        for (int e = 0; e < 4; ++e) {
            const float lo = t[(cg << 3) + 2 * e][px];
            const float hi = t[(cg << 3) + 2 * e + 1][px];
            asm("v_cvt_pk_bf16_f32 %0, %1, %2" : "=v"(pk[e]) : "v"(lo), "v"(hi));
        }
        *(uint4*)(xT + (((size_t)b << 20) + ((size_t)((h << 7) + px) << 6) + (cg << 3))) =
            make_uint4(pk[0], pk[1], pk[2], pk[3]);
    }
}

// ---------------------------------------------------------------------------
// Kernel 1: conv3x3 -> offset/mask, v2. Block = 64px x 32o, 4 waves.
// ALL 9 weight slices staged once into LDS (36 KB, XOR-swizzled
// byte ^= (row&7)<<4 — the R9-verified scheme that measured 0 bank
// conflicts). The k-loop is then pure ds_read + MFMA: NO barriers, NO
// per-tap staging (R7 version paid a __syncthreads + dbuf write per tap —
// ~31 µs by budget arithmetic). LDS 63.8 KB -> 2 blocks/CU; acceptable
// because the loop has no global-latency to hide (unlike deform, R9 lesson).
// ---------------------------------------------------------------------------
__global__ __launch_bounds__(256) void conv_om_mfma(
        const unsigned short* __restrict__ xT,
        const float* __restrict__ b_om,
        const unsigned short* __restrict__ wt_om16,  // [9][32][64]
        float* __restrict__ offm) {
    __shared__ __align__(16) unsigned short win[198 * 72];     // [3*66][72]
    __shared__ __align__(16) unsigned short wksAll[9 * 32 * 64]; // swizzled

    const int tid = threadIdx.x;
    const int bid = blockIdx.x;
    const int swz = ((bid & 7) << 8) + (bid >> 3);   // XCD-contiguous
    const int b = swz >> 8;
    const int rem = swz & 255;
    const int h = rem >> 1;
    const int w0 = (rem & 1) << 6;
    const int wid = tid >> 6;
    const int lane = tid & 63;
    const int ln15 = lane & 15;
    const int quad = lane >> 4;

    // stage 3-row, 66-px window of xT (zero-padded at borders)
    for (int idx = tid; idx < 1584; idx += 256) {
        const int pos = idx >> 3;
        const int part = idx & 7;
        const int r = pos / 66;
        const int xx = pos - r * 66;
        const int y = h + r - 1;
        const int xg = w0 + xx - 1;
        uint4 v = make_uint4(0u, 0u, 0u, 0u);
        if (y >= 0 && y < IH && xg >= 0 && xg < IW)
            v = *(const uint4*)(xT + (((size_t)b << 20) + (((y << 7) + xg) << 6) + (part << 3)));
        *(uint4*)&win[pos * 72 + part * 8] = v;
    }
    // stage ALL 9 weight slices, XOR-swizzled: byte col ^= (row&7)<<4
    for (int s = tid; s < 9 * 256; s += 256) {
        const int slice = s >> 8;        // 0..8
        const int idx = s & 255;
        const int o = idx >> 3;          // row 0..31
        const int sp = idx & 7;          // 16B part
        const int col = (sp << 4) ^ ((o & 7) << 4);   // swizzled byte col
        *(uint4*)&wksAll[(slice << 11) + (o << 6) + (col >> 1)] =
            *(const uint4*)(wt_om16 + (slice << 11) + (o << 6) + (sp << 3));
    }
    __syncthreads();

    f32x4 acc[2] = {{0.f, 0.f, 0.f, 0.f}, {0.f, 0.f, 0.f, 0.f}};

#pragma unroll
    for (int k = 0; k < 9; ++k) {
        const int kh = k / 3;
        const int kw = k - kh * 3;
        const int posb = kh * 66 + wid * 16 + ln15 + kw;
        const unsigned short* wb = &wksAll[k << 11];
        const int xr = (ln15 & 7) << 4;              // row-swizzle (same for
                                                     //  ln15 and 16+ln15)
#pragma unroll
        for (int ch = 0; ch < 2; ++ch) {
            const int c = (ch << 5) + (quad << 3);   // u16 col
            const int bcol = c << 1;                 // byte col (16B-aligned)
            U4B8 a, b0, b1;
            a.u  = *(const uint4*)&win[posb * 72 + c];
            b0.u = *(const uint4*)&wb[(ln15 << 6) + ((bcol ^ xr) >> 1)];
            b1.u = *(const uint4*)&wb[((16 + ln15) << 6) + ((bcol ^ xr) >> 1)];
            acc[0] = __builtin_amdgcn_mfma_f32_16x16x32_bf16(a.h, b0.h, acc[0], 0, 0, 0);
            acc[1] = __builtin_amdgcn_mfma_f32_16x16x32_bf16(a.h, b1.h, acc[1], 0, 0, 0);
        }
    }

    // C/D layout: col(o)=lane&15, row(px)=quad*4+reg
    const int px0 = wid * 16 + quad * 4;
#pragma unroll
    for (int ot = 0; ot < 2; ++ot) {
        const int o = (ot << 4) + ln15;
        if (o >= 27) continue;
        const float bias = b_om[o];
        float4 r;
        r.x = acc[ot][0] + bias;
        r.y = acc[ot][1] + bias;
        r.z = acc[ot][2] + bias;
        r.w = acc[ot][3] + bias;
        if (o >= 18) {
            r.x = 2.0f / (1.0f + __expf(-r.x));
            r.y = 2.0f / (1.0f + __expf(-r.y));
            r.z = 2.0f / (1.0f + __expf(-r.z));
            r.w = 2.0f / (1.0f + __expf(-r.w));
        }
        *(float4*)&offm[(((size_t)(b * 27 + o)) << 14) + (h << 7) + w0 + px0] = r;
    }
}

// ---------------------------------------------------------------------------
// gather issue phase: compute corner weights (msk premultiplied) and ISSUE
// the 8 corner loads into registers. Consumed one tap later.
// offs is LDS, stride OFFS_STRIDE floats per channel.
// ---------------------------------------------------------------------------
__device__ __forceinline__ void issue_gather(
        const unsigned short* __restrict__ xb, const float* offs,
        int k, int lpx, int h, int quad, uint4* g, float* cw) {
    const float offy = offs[(k << 1) * OFFS_STRIDE + lpx];
    const float offx = offs[((k << 1) + 1) * OFFS_STRIDE + lpx];
    const float msk  = offs[(18 + k) * OFFS_STRIDE + lpx];
    const int kh = k / 3;
    const int kw = k - kh * 3;
    const float py  = (float)(h + kh - 1) + offy;
    const float pxf = (float)(lpx + kw - 1) + offx;
    const float y0f = floorf(py);
    const float x0f = floorf(pxf);
    const float fy = py - y0f;
    const float fx = pxf - x0f;
    const float wy0 = 1.0f - fy, wx0 = 1.0f - fx;
    const float vy0 = (y0f >= 0.0f && y0f <= 127.0f) ? 1.0f : 0.0f;
    const float vy1 = (y0f >= -1.0f && y0f <= 126.0f) ? 1.0f : 0.0f;
    const float vx0 = (x0f >= 0.0f && x0f <= 127.0f) ? 1.0f : 0.0f;
    const float vx1 = (x0f >= -1.0f && x0f <= 126.0f) ? 1.0f : 0.0f;
    cw[0] = wy0 * wx0 * vy0 * vx0 * msk;
    cw[1] = wy0 * fx  * vy0 * vx1 * msk;
    cw[2] = fy  * wx0 * vy1 * vx0 * msk;
    cw[3] = fy  * fx  * vy1 * vx1 * msk;
    const int y0i = min(max((int)y0f, 0), 127);
    const int y1i = min(max((int)y0f + 1, 0), 127);
    const int x0i = min(max((int)x0f, 0), 127);
    const int x1i = min(max((int)x0f + 1, 0), 127);
    const int cofs = quad << 3;
    const unsigned short* p00 = xb + ((((size_t)((y0i << 7) + x0i)) << 6) + cofs);
    const unsigned short* p01 = xb + ((((size_t)((y0i << 7) + x1i)) << 6) + cofs);
    const unsigned short* p10 = xb + ((((size_t)((y1i << 7) + x0i)) << 6) + cofs);
    const unsigned short* p11 = xb + ((((size_t)((y1i << 7) + x1i)) << 6) + cofs);
    g[0] = *(const uint4*)p00;  g[1] = *(const uint4*)(p00 + 32);
    g[2] = *(const uint4*)p01;  g[3] = *(const uint4*)(p01 + 32);
    g[4] = *(const uint4*)p10;  g[5] = *(const uint4*)(p10 + 32);
    g[6] = *(const uint4*)p11;  g[7] = *(const uint4*)(p11 + 32);
}

// ---------------------------------------------------------------------------
// consume phase: combine 8 corner vectors with 4 (msk-premul) weights via
// packed-f32 FMA, pack to bf16 A-fragments via hw cvt_pk.
// ---------------------------------------------------------------------------
__device__ __forceinline__ void pack_frags(const uint4* g, const float* cw,
                                           U4B8& a0, U4B8& a1) {
    f32x2 v2[8];
#pragma unroll
    for (int i = 0; i < 8; ++i) v2[i] = (f32x2){0.f, 0.f};
#pragma unroll
    for (int c = 0; c < 4; ++c) {
        f32x2 w2;
        w2.x = cw[c];
        w2.y = cw[c];
        const uint4 ga = g[2 * c];
        const uint4 gb = g[2 * c + 1];
        const unsigned int u[8] = {ga.x, ga.y, ga.z, ga.w, gb.x, gb.y, gb.z, gb.w};
#pragma unroll
        for (int i = 0; i < 8; ++i) {
            f32x2 x2;
            x2.x = __uint_as_float(u[i] << 16);
            x2.y = __uint_as_float(u[i] & 0xffff0000u);
            asm("v_pk_fma_f32 %0, %1, %2, %0" : "+v"(v2[i]) : "v"(x2), "v"(w2));
        }
    }
    unsigned int pk[8];
#pragma unroll
    for (int i = 0; i < 8; ++i)
        asm("v_cvt_pk_bf16_f32 %0, %1, %2"
            : "=v"(pk[i]) : "v"(v2[i].x), "v"(v2[i].y));
    a0.u = make_uint4(pk[0], pk[1], pk[2], pk[3]);
    a1.u = make_uint4(pk[4], pk[5], pk[6], pk[7]);
}

// ---------------------------------------------------------------------------
// Kernel 2: deformable conv — R7 version VERBATIM (77.4 µs, best of the 4
// structural variants tested R0/R4/R7/R9; R9 proved conflicts/barriers were
// not the binding constraint, residency is). Block = 128px x 64o, 8 waves.
// ---------------------------------------------------------------------------
__global__ __launch_bounds__(512) void deform_mfma(
        const unsigned short* __restrict__ xT,
        const float* __restrict__ b_dc,
        const float* __restrict__ offm,              // [B][27][H][W]
        const unsigned short* __restrict__ wt_dc16,  // [9][64][64] (k,o,c)
        float* __restrict__ out) {
    __shared__ __align__(16) float offs[27 * OFFS_STRIDE];   // [ch][px]
    __shared__ __align__(16) unsigned short wks[2][64 * 72]; // [buf][o][72]

    const int tid = threadIdx.x;
    const int bid = blockIdx.x;
    const int swz = ((bid & 7) << 7) + (bid >> 3);   // XCD-contiguous (1024)
    const int b = swz >> 7;
    const int h = swz & 127;
    const int wid = tid >> 6;            // 0..7
    const int lane = tid & 63;
    const int ln15 = lane & 15;
    const int quad = lane >> 4;
    const int lpx = (wid << 4) + ln15;   // 0..127: pixel this lane owns

    // stage offsets/masks for the row's 128 pixels
    for (int i = tid; i < 27 * 128; i += 512) {
        const int ch = i >> 7;
        const int px = i & 127;
        offs[ch * OFFS_STRIDE + px] =
            offm[(((size_t)(b * 27 + ch)) << 14) + (h << 7) + px];
    }
    // stage weights k=0 into wks[0]: exactly 512 uint4 slots, 1 per thread
    const int so = tid >> 3, sp = tid & 7;
    *(uint4*)&wks[0][so * 72 + sp * 8] =
        *(const uint4*)(wt_dc16 + (so << 6) + (sp << 3));
    __syncthreads();

    const unsigned short* xb = xT + ((size_t)b << 20);

    f32x4 acc[4];
#pragma unroll
    for (int i = 0; i < 4; ++i) acc[i] = (f32x4){0.f, 0.f, 0.f, 0.f};

    uint4 g[2][8];
    float cw[2][4];
    issue_gather(xb, offs, 0, lpx, h, quad, g[0], cw[0]);

#pragma unroll
    for (int k = 0; k < 9; ++k) {
        const int cur = k & 1;
        const int nxt = cur ^ 1;
        if (k < 8) {
            // 1) weight load for k+1 (oldest in this iter's vmem FIFO)
            const uint4 wv = *(const uint4*)(wt_dc16 + ((k + 1) << 12) + (so << 6) + (sp << 3));
            // 2) issue next-tap gather loads (newest — stay in flight)
            issue_gather(xb, offs, k + 1, lpx, h, quad, g[nxt], cw[nxt]);
            // 3) ds_write W: waits vmcnt(8) -> drains W + gather(k) only
            *(uint4*)&wks[nxt][so * 72 + sp * 8] = wv;
        }
        // 4) pack tap k from last iteration's registers
        U4B8 a0, a1;
        pack_frags(g[cur], cw[cur], a0, a1);
        // 5) MFMA from LDS weight broadcast
        const unsigned short* wb = wks[cur];
#pragma unroll
        for (int ot = 0; ot < 4; ++ot) {
            U4B8 b0, b1;
            const unsigned short* base = &wb[((ot << 4) + ln15) * 72 + (quad << 3)];
            b0.u = *(const uint4*)base;
            b1.u = *(const uint4*)(base + 32);
            acc[ot] = __builtin_amdgcn_mfma_f32_16x16x32_bf16(a0.h, b0.h, acc[ot], 0, 0, 0);
            acc[ot] = __builtin_amdgcn_mfma_f32_16x16x32_bf16(a1.h, b1.h, acc[ot], 0, 0, 0);
        }
        // 6) dbuf barrier: LDS-only wait — gather(k+1) loads stay in flight
        if (k < 8) {
            asm volatile("s_waitcnt lgkmcnt(0)" ::: "memory");
            __builtin_amdgcn_s_barrier();
            __builtin_amdgcn_sched_barrier(0);
        }
    }

    // epilogue: col(o)=lane&15, row(px)=quad*4+reg
#pragma unroll
    for (int ot = 0; ot < 4; ++ot) {
        const int o = (ot << 4) + ln15;
        const float bias = b_dc[o];
        float4 r;
        r.x = acc[ot][0] + bias;
        r.y = acc[ot][1] + bias;
        r.z = acc[ot][2] + bias;
        r.w = acc[ot][3] + bias;
        *(float4*)&out[(((size_t)(b * 64 + o)) << 14) + (h << 7) + (wid << 4) + (quad << 2)] = r;
    }
}

extern "C" void kernel_launch(void* const* d_in, const int* in_sizes, int n_in,
                              void* d_out, int out_size, void* d_ws, size_t ws_size,
                              hipStream_t stream) {
    const float* x    = (const float*)d_in[0];
    const float* w_om = (const float*)d_in[1];
    const float* b_om = (const float*)d_in[2];
    const float* w_dc = (const float*)d_in[3];
    const float* b_dc = (const float*)d_in[4];
    float* out = (float*)d_out;
    float* ws  = (float*)d_ws;

    float* offm = ws + OFFM_OFF;
    unsigned short* xT      = (unsigned short*)(ws + XT_OFF);
    unsigned short* wt_dc16 = (unsigned short*)(ws + WTDC_OFF);
    unsigned short* wt_om16 = (unsigned short*)(ws + WTOM_OFF);

    transpose_x_w<<<NB * IH + 144, 256, 0, stream>>>(x, xT, w_dc, w_om, wt_dc16, wt_om16);
    conv_om_mfma<<<NB * IH * 2, 256, 0, stream>>>(xT, b_om, wt_om16, offm);
    deform_mfma<<<NB * IH, 512, 0, stream>>>(xT, b_dc, offm, wt_dc16, out);
}

// Round 11
// 179.015 us; speedup vs baseline: 1.0869x; 1.0332x over previous
//
#include <hip/hip_runtime.h>
#include <cmath>

#define IH 128
#define IW 128
#define NB 8
#define OFFS_STRIDE 129

typedef __attribute__((ext_vector_type(8))) short bf16x8;
typedef __attribute__((ext_vector_type(4))) float f32x4;
typedef __attribute__((ext_vector_type(2))) float f32x2;

union U4B8 { uint4 u; bf16x8 h; };

// ws layout (float slots):
//   offm  : [NB][27][IH][IW] f32      = 3538944
//   xT    : [NB][IH][IW][64] bf16     = 4194304 float slots (8388608 u16)
//   wt_dc : [9][64][64] bf16 (k,o,c)  = 18432 float slots
//   wt_om : [9][32][64] bf16 (k,o,c)  = 9216  float slots
#define OFFM_OFF 0
#define XT_OFF   3538944
#define WTDC_OFF (3538944 + 4194304)
#define WTOM_OFF (3538944 + 4194304 + 18432)

// fp32 -> bf16 bits, round-to-nearest-even
__device__ __forceinline__ unsigned short f32_to_bf16(float f) {
    unsigned int u = __float_as_uint(f);
    u += 0x7fffu + ((u >> 16) & 1u);
    return (unsigned short)(u >> 16);
}

// ---------------------------------------------------------------------------
// Kernel 0: x NCHW fp32 -> NHWC bf16 (blocks 0..1023, vectorized)
//           + weights -> bf16 [k][o][c] (tail blocks) — merged launch.
// ---------------------------------------------------------------------------
__global__ __launch_bounds__(256) void transpose_x_w(
        const float* __restrict__ x, unsigned short* __restrict__ xT,
        const float* __restrict__ w_dc, const float* __restrict__ w_om,
        unsigned short* __restrict__ wt_dc16,
        unsigned short* __restrict__ wt_om16) {
    __shared__ __align__(16) float t[64][132];   // 132: 16B-aligned rows, +pad
    const int tid = threadIdx.x;
    const int blk = blockIdx.x;

    if (blk >= NB * IH) {            // weight-transpose tail blocks
        const int idx = (blk - NB * IH) * 256 + tid;
        if (idx < 9 * 64 * 64) {
            const int k = idx >> 12;
            const int o = (idx >> 6) & 63;
            const int c = idx & 63;
            wt_dc16[idx] = f32_to_bf16(w_dc[(o * 64 + c) * 9 + k]);
        }
        if (idx < 9 * 32 * 64) {
            const int k = idx >> 11;
            const int o = (idx >> 6) & 31;
            const int c = idx & 63;
            wt_om16[idx] = (o < 27) ? f32_to_bf16(w_om[(o * 64 + c) * 9 + k])
                                    : (unsigned short)0;
        }
        return;
    }

    const int b = blk >> 7;
    const int h = blk & 127;

#pragma unroll
    for (int j = 0; j < 8; ++j) {
        const int i = (j << 8) + tid;       // 0..2047
        const int c = i >> 5;               // 0..63
        const int w4 = i & 31;              // float4 index within row
        const float4 v = *(const float4*)&x[(((size_t)(b * 64 + c)) << 14) + (h << 7) + (w4 << 2)];
        *(float4*)&t[c][w4 << 2] = v;
    }
    __syncthreads();

#pragma unroll
    for (int j = 0; j < 4; ++j) {
        const int u = (j << 8) + tid;       // 0..1023
        const int px = u & 127;
        const int cg = u >> 7;              // channel-group of 8
        unsigned int pk[4];
#pragma unroll
        for (int e = 0; e < 4; ++e) {
            const float lo = t[(cg << 3) + 2 * e][px];
            const float hi = t[(cg << 3) + 2 * e + 1][px];
            asm("v_cvt_pk_bf16_f32 %0, %1, %2" : "=v"(pk[e]) : "v"(lo), "v"(hi));
        }
        *(uint4*)(xT + (((size_t)b << 20) + ((size_t)((h << 7) + px) << 6) + (cg << 3))) =
            make_uint4(pk[0], pk[1], pk[2], pk[3]);
    }
}

// ---------------------------------------------------------------------------
// Kernel 1: conv3x3 -> offset/mask — R3 double-buffered version, reverted
// (R10's whole-weight-LDS v2 cost ~4 µs via the 2-blocks/CU residency hit;
// R9 lesson: residency beats barrier-elimination for short loops).
// ---------------------------------------------------------------------------
__global__ __launch_bounds__(256) void conv_om_mfma(
        const unsigned short* __restrict__ xT,
        const float* __restrict__ b_om,
        const unsigned short* __restrict__ wt_om16,  // [9][32][64]
        float* __restrict__ offm) {
    __shared__ __align__(16) unsigned short win[198 * 72];   // [3*66][72]
    __shared__ __align__(16) unsigned short wks[2][32 * 72]; // [buf][o][72]

    const int tid = threadIdx.x;
    const int bid = blockIdx.x;
    const int swz = ((bid & 7) << 8) + (bid >> 3);   // XCD-contiguous
    const int b = swz >> 8;
    const int rem = swz & 255;
    const int h = rem >> 1;
    const int w0 = (rem & 1) << 6;
    const int wid = tid >> 6;
    const int lane = tid & 63;
    const int ln15 = lane & 15;
    const int quad = lane >> 4;

    for (int idx = tid; idx < 1584; idx += 256) {
        const int pos = idx >> 3;
        const int part = idx & 7;
        const int r = pos / 66;
        const int xx = pos - r * 66;
        const int y = h + r - 1;
        const int xg = w0 + xx - 1;
        uint4 v = make_uint4(0u, 0u, 0u, 0u);
        if (y >= 0 && y < IH && xg >= 0 && xg < IW)
            v = *(const uint4*)(xT + (((size_t)b << 20) + (((y << 7) + xg) << 6) + (part << 3)));
        *(uint4*)&win[pos * 72 + part * 8] = v;
    }
    {
        const int o = tid >> 3;
        const int part = tid & 7;
        *(uint4*)&wks[0][o * 72 + part * 8] =
            *(const uint4*)(wt_om16 + (o << 6) + (part << 3));
    }
    __syncthreads();

    f32x4 acc[2] = {{0.f, 0.f, 0.f, 0.f}, {0.f, 0.f, 0.f, 0.f}};

    for (int k = 0; k < 9; ++k) {
        const int buf = k & 1;
        if (k < 8) {
            const int o = tid >> 3;
            const int part = tid & 7;
            *(uint4*)&wks[buf ^ 1][o * 72 + part * 8] =
                *(const uint4*)(wt_om16 + ((k + 1) << 11) + (o << 6) + (part << 3));
        }
        const int kh = k / 3;
        const int kw = k - kh * 3;
        const int posb = kh * 66 + wid * 16 + ln15 + kw;
        const unsigned short* wb = wks[buf];
#pragma unroll
        for (int ch = 0; ch < 2; ++ch) {
            const int c = (ch << 5) + (quad << 3);
            U4B8 a, b0, b1;
            a.u  = *(const uint4*)&win[posb * 72 + c];
            b0.u = *(const uint4*)&wb[ln15 * 72 + c];
            b1.u = *(const uint4*)&wb[(16 + ln15) * 72 + c];
            acc[0] = __builtin_amdgcn_mfma_f32_16x16x32_bf16(a.h, b0.h, acc[0], 0, 0, 0);
            acc[1] = __builtin_amdgcn_mfma_f32_16x16x32_bf16(a.h, b1.h, acc[1], 0, 0, 0);
        }
        __syncthreads();
    }

    const int px0 = wid * 16 + quad * 4;
#pragma unroll
    for (int ot = 0; ot < 2; ++ot) {
        const int o = (ot << 4) + ln15;
        if (o >= 27) continue;
        const float bias = b_om[o];
        float4 r;
        r.x = acc[ot][0] + bias;
        r.y = acc[ot][1] + bias;
        r.z = acc[ot][2] + bias;
        r.w = acc[ot][3] + bias;
        if (o >= 18) {
            r.x = 2.0f / (1.0f + __expf(-r.x));
            r.y = 2.0f / (1.0f + __expf(-r.y));
            r.z = 2.0f / (1.0f + __expf(-r.z));
            r.w = 2.0f / (1.0f + __expf(-r.w));
        }
        *(float4*)&offm[(((size_t)(b * 27 + o)) << 14) + (h << 7) + w0 + px0] = r;
    }
}

// ---------------------------------------------------------------------------
// gather issue phase: compute corner weights (msk premultiplied) and ISSUE
// the 8 corner loads into registers. Consumed one tap later.
// ---------------------------------------------------------------------------
__device__ __forceinline__ void issue_gather(
        const unsigned short* __restrict__ xb, const float* offs,
        int k, int lpx, int h, int quad, uint4* g, float* cw) {
    const float offy = offs[(k << 1) * OFFS_STRIDE + lpx];
    const float offx = offs[((k << 1) + 1) * OFFS_STRIDE + lpx];
    const float msk  = offs[(18 + k) * OFFS_STRIDE + lpx];
    const int kh = k / 3;
    const int kw = k - kh * 3;
    const float py  = (float)(h + kh - 1) + offy;
    const float pxf = (float)(lpx + kw - 1) + offx;
    const float y0f = floorf(py);
    const float x0f = floorf(pxf);
    const float fy = py - y0f;
    const float fx = pxf - x0f;
    const float wy0 = 1.0f - fy, wx0 = 1.0f - fx;
    const float vy0 = (y0f >= 0.0f && y0f <= 127.0f) ? 1.0f : 0.0f;
    const float vy1 = (y0f >= -1.0f && y0f <= 126.0f) ? 1.0f : 0.0f;
    const float vx0 = (x0f >= 0.0f && x0f <= 127.0f) ? 1.0f : 0.0f;
    const float vx1 = (x0f >= -1.0f && x0f <= 126.0f) ? 1.0f : 0.0f;
    cw[0] = wy0 * wx0 * vy0 * vx0 * msk;
    cw[1] = wy0 * fx  * vy0 * vx1 * msk;
    cw[2] = fy  * wx0 * vy1 * vx0 * msk;
    cw[3] = fy  * fx  * vy1 * vx1 * msk;
    const int y0i = min(max((int)y0f, 0), 127);
    const int y1i = min(max((int)y0f + 1, 0), 127);
    const int x0i = min(max((int)x0f, 0), 127);
    const int x1i = min(max((int)x0f + 1, 0), 127);
    const int cofs = quad << 3;
    const unsigned short* p00 = xb + ((((size_t)((y0i << 7) + x0i)) << 6) + cofs);
    const unsigned short* p01 = xb + ((((size_t)((y0i << 7) + x1i)) << 6) + cofs);
    const unsigned short* p10 = xb + ((((size_t)((y1i << 7) + x0i)) << 6) + cofs);
    const unsigned short* p11 = xb + ((((size_t)((y1i << 7) + x1i)) << 6) + cofs);
    g[0] = *(const uint4*)p00;  g[1] = *(const uint4*)(p00 + 32);
    g[2] = *(const uint4*)p01;  g[3] = *(const uint4*)(p01 + 32);
    g[4] = *(const uint4*)p10;  g[5] = *(const uint4*)(p10 + 32);
    g[6] = *(const uint4*)p11;  g[7] = *(const uint4*)(p11 + 32);
}

// ---------------------------------------------------------------------------
// consume phase: combine 8 corner vectors with 4 (msk-premul) weights via
// packed-f32 FMA, pack to bf16 A-fragments via hw cvt_pk.
// ---------------------------------------------------------------------------
__device__ __forceinline__ void pack_frags(const uint4* g, const float* cw,
                                           U4B8& a0, U4B8& a1) {
    f32x2 v2[8];
#pragma unroll
    for (int i = 0; i < 8; ++i) v2[i] = (f32x2){0.f, 0.f};
#pragma unroll
    for (int c = 0; c < 4; ++c) {
        f32x2 w2;
        w2.x = cw[c];
        w2.y = cw[c];
        const uint4 ga = g[2 * c];
        const uint4 gb = g[2 * c + 1];
        const unsigned int u[8] = {ga.x, ga.y, ga.z, ga.w, gb.x, gb.y, gb.z, gb.w};
#pragma unroll
        for (int i = 0; i < 8; ++i) {
            f32x2 x2;
            x2.x = __uint_as_float(u[i] << 16);
            x2.y = __uint_as_float(u[i] & 0xffff0000u);
            asm("v_pk_fma_f32 %0, %1, %2, %0" : "+v"(v2[i]) : "v"(x2), "v"(w2));
        }
    }
    unsigned int pk[8];
#pragma unroll
    for (int i = 0; i < 8; ++i)
        asm("v_cvt_pk_bf16_f32 %0, %1, %2"
            : "=v"(pk[i]) : "v"(v2[i].x), "v"(v2[i].y));
    a0.u = make_uint4(pk[0], pk[1], pk[2], pk[3]);
    a1.u = make_uint4(pk[4], pk[5], pk[6], pk[7]);
}

// ---------------------------------------------------------------------------
// Kernel 2: deformable conv. Block = 128px x 64o, 8 waves (R7 structure),
// but __launch_bounds__(512, 4): VGPR cap 128 instead of the compiler's
// default 8-waves/EU target that collapsed the gather pipeline to 64 VGPR
// (R7/R10). This is the untested quadrant: pipeline KEPT (like R4's VGPR=84)
// AND the halved 128-px staging overhead (like R7). R9 proved the natural
// pipelined allocation is ~88 regs — fits the 128 cap without spills.
// ---------------------------------------------------------------------------
__global__ __launch_bounds__(512, 4) void deform_mfma(
        const unsigned short* __restrict__ xT,
        const float* __restrict__ b_dc,
        const float* __restrict__ offm,              // [B][27][H][W]
        const unsigned short* __restrict__ wt_dc16,  // [9][64][64] (k,o,c)
        float* __restrict__ out) {
    __shared__ __align__(16) float offs[27 * OFFS_STRIDE];   // [ch][px]
    __shared__ __align__(16) unsigned short wks[2][64 * 72]; // [buf][o][72]

    const int tid = threadIdx.x;
    const int bid = blockIdx.x;
    const int swz = ((bid & 7) << 7) + (bid >> 3);   // XCD-contiguous (1024)
    const int b = swz >> 7;
    const int h = swz & 127;
    const int wid = tid >> 6;            // 0..7
    const int lane = tid & 63;
    const int ln15 = lane & 15;
    const int quad = lane >> 4;
    const int lpx = (wid << 4) + ln15;   // 0..127: pixel this lane owns

    // stage offsets/masks for the row's 128 pixels
    for (int i = tid; i < 27 * 128; i += 512) {
        const int ch = i >> 7;
        const int px = i & 127;
        offs[ch * OFFS_STRIDE + px] =
            offm[(((size_t)(b * 27 + ch)) << 14) + (h << 7) + px];
    }
    // stage weights k=0 into wks[0]: exactly 512 uint4 slots, 1 per thread
    const int so = tid >> 3, sp = tid & 7;
    *(uint4*)&wks[0][so * 72 + sp * 8] =
        *(const uint4*)(wt_dc16 + (so << 6) + (sp << 3));
    __syncthreads();

    const unsigned short* xb = xT + ((size_t)b << 20);

    f32x4 acc[4];
#pragma unroll
    for (int i = 0; i < 4; ++i) acc[i] = (f32x4){0.f, 0.f, 0.f, 0.f};

    uint4 g[2][8];
    float cw[2][4];
    issue_gather(xb, offs, 0, lpx, h, quad, g[0], cw[0]);

#pragma unroll
    for (int k = 0; k < 9; ++k) {
        const int cur = k & 1;
        const int nxt = cur ^ 1;
        if (k < 8) {
            // 1) weight load for k+1 (oldest in this iter's vmem FIFO)
            const uint4 wv = *(const uint4*)(wt_dc16 + ((k + 1) << 12) + (so << 6) + (sp << 3));
            // 2) issue next-tap gather loads (newest — stay in flight)
            issue_gather(xb, offs, k + 1, lpx, h, quad, g[nxt], cw[nxt]);
            // 3) ds_write W: waits vmcnt(8) -> drains W + gather(k) only
            *(uint4*)&wks[nxt][so * 72 + sp * 8] = wv;
        }
        // 4) pack tap k from last iteration's registers
        U4B8 a0, a1;
        pack_frags(g[cur], cw[cur], a0, a1);
        // 5) MFMA from LDS weight broadcast
        const unsigned short* wb = wks[cur];
#pragma unroll
        for (int ot = 0; ot < 4; ++ot) {
            U4B8 b0, b1;
            const unsigned short* base = &wb[((ot << 4) + ln15) * 72 + (quad << 3)];
            b0.u = *(const uint4*)base;
            b1.u = *(const uint4*)(base + 32);
            acc[ot] = __builtin_amdgcn_mfma_f32_16x16x32_bf16(a0.h, b0.h, acc[ot], 0, 0, 0);
            acc[ot] = __builtin_amdgcn_mfma_f32_16x16x32_bf16(a1.h, b1.h, acc[ot], 0, 0, 0);
        }
        // 6) dbuf barrier: LDS-only wait — gather(k+1) loads stay in flight
        if (k < 8) {
            asm volatile("s_waitcnt lgkmcnt(0)" ::: "memory");
            __builtin_amdgcn_s_barrier();
            __builtin_amdgcn_sched_barrier(0);
        }
    }

    // epilogue: col(o)=lane&15, row(px)=quad*4+reg
#pragma unroll
    for (int ot = 0; ot < 4; ++ot) {
        const int o = (ot << 4) + ln15;
        const float bias = b_dc[o];
        float4 r;
        r.x = acc[ot][0] + bias;
        r.y = acc[ot][1] + bias;
        r.z = acc[ot][2] + bias;
        r.w = acc[ot][3] + bias;
        *(float4*)&out[(((size_t)(b * 64 + o)) << 14) + (h << 7) + (wid << 4) + (quad << 2)] = r;
    }
}

extern "C" void kernel_launch(void* const* d_in, const int* in_sizes, int n_in,
                              void* d_out, int out_size, void* d_ws, size_t ws_size,
                              hipStream_t stream) {
    const float* x    = (const float*)d_in[0];
    const float* w_om = (const float*)d_in[1];
    const float* b_om = (const float*)d_in[2];
    const float* w_dc = (const float*)d_in[3];
    const float* b_dc = (const float*)d_in[4];
    float* out = (float*)d_out;
    float* ws  = (float*)d_ws;

    float* offm = ws + OFFM_OFF;
    unsigned short* xT      = (unsigned short*)(ws + XT_OFF);
    unsigned short* wt_dc16 = (unsigned short*)(ws + WTDC_OFF);
    unsigned short* wt_om16 = (unsigned short*)(ws + WTOM_OFF);

    transpose_x_w<<<NB * IH + 144, 256, 0, stream>>>(x, xT, w_dc, w_om, wt_dc16, wt_om16);
    conv_om_mfma<<<NB * IH * 2, 256, 0, stream>>>(xT, b_om, wt_om16, offm);
    deform_mfma<<<NB * IH, 512, 0, stream>>>(xT, b_dc, offm, wt_dc16, out);
}